// Round 1
// 907.912 us; speedup vs baseline: 1.0045x; 1.0045x over previous
//
#include <hip/hip_runtime.h>
#include <hip/hip_bf16.h>
#include <stdint.h>

typedef __bf16 v8bf __attribute__((ext_vector_type(8)));
typedef float  v4f  __attribute__((ext_vector_type(4)));
typedef unsigned short u16;
typedef unsigned int   u32;

#define B_ROWS   8192
#define N_SUP    100000
#define N_CLS    1000
#define CPAD     1024
#define DIM      768
#define MSUP_PAD 100352   // 784 * 128

// ---------- helpers ----------
__device__ __forceinline__ u16 f2bf(float f) {
    union { float f; u32 u; } v; v.f = f;
    u32 r = 0x7FFFu + ((v.u >> 16) & 1u);   // RNE
    return (u16)((v.u + r) >> 16);
}
__device__ __forceinline__ float bf2f(u16 b) {
    union { u32 u; float f; } v; v.u = ((u32)b) << 16; return v.f;
}
// async global->LDS, 16B per lane; LDS dst = wave-uniform base + lane*16
__device__ __forceinline__ void glds16(const void* g, void* l) {
    __builtin_amdgcn_global_load_lds((const __attribute__((address_space(1))) u32*)g,
                                     (__attribute__((address_space(3))) u32*)l, 16, 0, 0);
}

__device__ __forceinline__ float block_sum(float v, float* red) {
    #pragma unroll
    for (int o = 32; o > 0; o >>= 1) v += __shfl_down(v, o);
    int wv = threadIdx.x >> 6, ln = threadIdx.x & 63;
    if (ln == 0) red[wv] = v;
    __syncthreads();
    return red[0] + red[1] + red[2] + red[3];
}
__device__ __forceinline__ float block_max(float v, float* red) {
    #pragma unroll
    for (int o = 32; o > 0; o >>= 1) v = fmaxf(v, __shfl_down(v, o));
    int wv = threadIdx.x >> 6, ln = threadIdx.x & 63;
    if (ln == 0) red[wv] = v;
    __syncthreads();
    return fmaxf(fmaxf(red[0], red[1]), fmaxf(red[2], red[3]));
}

// XCD chunked bijective swizzle (requires nwg % 8 == 0; true for all grids here)
__device__ __forceinline__ int xcd_swizzle(void) {
    const int nwg = gridDim.x * gridDim.y;
    const int bid = blockIdx.y * gridDim.x + blockIdx.x;
    const int q = nwg >> 3;
    return (bid & 7) * q + (bid >> 3);
}

// ---------- fp32 -> bf16 conversion, zero-pad rows >= n_real ----------
// one block per 4 rows, 256 thr, 3 float4 per thr (4*768 = 3072 elems = 768 f4)
__global__ __launch_bounds__(256)
void conv_pad_kernel(const float* __restrict__ in, u16* __restrict__ out,
                     int n_real) {
    #pragma unroll
    for (int s = 0; s < 3; s++) {
        size_t f4 = (size_t)blockIdx.x * 768 + s * 256 + threadIdx.x;
        int row = (int)(f4 / 192);            // 192 float4 per row
        size_t eb = f4 * 4;
        ushort4 o;
        if (row < n_real) {
            float4 v = *(const float4*)(in + eb);
            o.x = f2bf(v.x); o.y = f2bf(v.y); o.z = f2bf(v.z); o.w = f2bf(v.w);
        } else {
            o.x = 0; o.y = 0; o.z = 0; o.w = 0;
        }
        *(ushort4*)(out + eb) = o;
    }
}

// ---------- adapter GEMM: h = A @ W^T + b; epilogue val = silu(h)+t, row ss ----------
// A bf16 [M,768] (M % 128 == 0, padded rows zero), Wb bf16 [768,768].
// t re-read from A (bf16). grid = (6, M/128), block = 256.
// 2-phase double-buffered pipeline: prefetch tile t+1 before computing tile t,
// ONE barrier per K-step (implicit vmcnt(0)+lgkmcnt(0) drain at __syncthreads).
__global__ __launch_bounds__(256)
void adapter_gemm_kernel(const u16* __restrict__ A, const u16* __restrict__ Wb,
                         const float* __restrict__ bias,
                         u16* __restrict__ val, float* __restrict__ ss) {
    __shared__ u16 As[2][128 * 64];
    __shared__ u16 Bs[2][128 * 64];

    const int tid  = threadIdx.x;
    const int wave = tid >> 6, lane = tid & 63;
    const int fq = lane >> 4, fr = lane & 15;

    const int swz = xcd_swizzle();
    const int blk_m = (swz / gridDim.x) * 128;
    const int blk_n = (swz % gridDim.x) * 128;

    const int wm = (wave & 1) * 64, wn = (wave >> 1) * 64;

    v4f acc[4][4];
    #pragma unroll
    for (int i = 0; i < 4; i++)
        #pragma unroll
        for (int j = 0; j < 4; j++) acc[i][j] = (v4f){0.f, 0.f, 0.f, 0.f};

    const int rb = lane >> 3;           // 0..7 rows within a wave's 8-row strip
    const int cb = (lane & 7) * 8;      // col elems (16B)
    const u16* gA = A  + (size_t)(blk_m + wave * 8 + rb) * DIM + cb;
    const u16* gB = Wb + (size_t)(blk_n + wave * 8 + rb) * DIM + cb;

    auto STAGE = [&](int buf, int k0) {
        #pragma unroll
        for (int p = 0; p < 4; p++) {
            glds16(gA + (size_t)p * 32 * DIM + k0, &As[buf][p * 2048 + wave * 512]);
            glds16(gB + (size_t)p * 32 * DIM + k0, &Bs[buf][p * 2048 + wave * 512]);
        }
    };
    auto COMPUTE = [&](int buf) {
        #pragma unroll
        for (int ks = 0; ks < 2; ks++) {
            const int kk = ks * 32;
            v8bf af[4], bfr[4];
            #pragma unroll
            for (int i = 0; i < 4; i++) {
                af[i]  = *(const v8bf*)(&As[buf][(wm + i * 16 + fr) * 64 + kk + fq * 8]);
                bfr[i] = *(const v8bf*)(&Bs[buf][(wn + i * 16 + fr) * 64 + kk + fq * 8]);
            }
            #pragma unroll
            for (int i = 0; i < 4; i++)
                #pragma unroll
                for (int j = 0; j < 4; j++)
                    acc[i][j] = __builtin_amdgcn_mfma_f32_16x16x32_bf16(
                        af[i], bfr[j], acc[i][j], 0, 0, 0);
        }
    };

    STAGE(0, 0);
    __syncthreads();                 // drain: buf0 staged
    int cur = 0;
    for (int k0 = 64; k0 < DIM; k0 += 64) {
        STAGE(cur ^ 1, k0);          // prefetch next tile (in flight during MFMA)
        COMPUTE(cur);
        __syncthreads();             // single barrier/K-step: prefetch landed
        cur ^= 1;
    }
    COMPUTE(cur);                    // last tile

    // epilogue: val = silu(h) + t (t from bf16 A); write val bf16; row ss -> atomic
    #pragma unroll
    for (int i = 0; i < 4; i++) {
        int r0 = blk_m + wm + i * 16 + fq * 4;
        float ssp[4] = {0.f, 0.f, 0.f, 0.f};
        #pragma unroll
        for (int j = 0; j < 4; j++) {
            int col = blk_n + wn + j * 16 + fr;
            float bv = bias[col];
            #pragma unroll
            for (int r2 = 0; r2 < 4; r2++) {
                int gr = r0 + r2;
                float h = acc[i][j][r2] + bv;
                float t = bf2f(A[(size_t)gr * DIM + col]);
                float v = h / (1.f + __expf(-h)) + t;
                ssp[r2] += v * v;
                val[(size_t)gr * DIM + col] = f2bf(v);
            }
        }
        #pragma unroll
        for (int r2 = 0; r2 < 4; r2++) {
            float s = ssp[r2];
            s += __shfl_xor(s, 1); s += __shfl_xor(s, 2);
            s += __shfl_xor(s, 4); s += __shfl_xor(s, 8);
            if (fr == 0) atomicAdd(&ss[r0 + r2], s);
        }
    }
}

// ---------- x normalize: emb = val / max(||val||, eps); fp32 + bf16 out ----------
__global__ void norm_x_kernel(const u16* __restrict__ val, const float* __restrict__ ss,
                              float* __restrict__ emb, u16* __restrict__ emb_bf) {
    int row = blockIdx.x;
    float sc = 1.f / fmaxf(sqrtf(ss[row]), 1e-12f);
    size_t b = (size_t)row * DIM + threadIdx.x * 4;
    ushort4 v = *(const ushort4*)(val + b);
    float4 o;
    o.x = bf2f(v.x) * sc; o.y = bf2f(v.y) * sc;
    o.z = bf2f(v.z) * sc; o.w = bf2f(v.w) * sc;
    *(float4*)(emb + b) = o;
    ushort4 ob; ob.x = f2bf(o.x); ob.y = f2bf(o.y); ob.z = f2bf(o.z); ob.w = f2bf(o.w);
    *(ushort4*)(emb_bf + b) = ob;
}

// ---------- prototypes: one class per block; queue-gather, mean, l2norm ----------
__global__ __launch_bounds__(256)
void proto_kernel(const u16* __restrict__ val_bf, const float* __restrict__ ss,
                  const int* __restrict__ labels, u16* __restrict__ proto_bf) {
    __shared__ int queue[256];
    __shared__ int qn;
    __shared__ float red[4];
    const int cls = blockIdx.x, tid = threadIdx.x;
    if (tid == 0) qn = 0;
    __syncthreads();
    for (int i4 = tid; i4 < N_SUP / 4; i4 += 256) {
        int4 L = *(const int4*)(labels + i4 * 4);
        if (L.x == cls) queue[atomicAdd(&qn, 1) & 255] = i4 * 4;
        if (L.y == cls) queue[atomicAdd(&qn, 1) & 255] = i4 * 4 + 1;
        if (L.z == cls) queue[atomicAdd(&qn, 1) & 255] = i4 * 4 + 2;
        if (L.w == cls) queue[atomicAdd(&qn, 1) & 255] = i4 * 4 + 3;
    }
    __syncthreads();
    const int n = qn < 256 ? qn : 256;   // ~100 expected; cap unreachable
    float a0 = 0.f, a1 = 0.f, a2 = 0.f;
    for (int e = 0; e < n; e++) {
        int row = queue[e];
        float sc = 1.f / fmaxf(sqrtf(ss[row]), 1e-12f);
        const u16* vr = val_bf + (size_t)row * DIM;
        a0 += bf2f(vr[tid])       * sc;
        a1 += bf2f(vr[tid + 256]) * sc;
        a2 += bf2f(vr[tid + 512]) * sc;
    }
    float inv_cnt = 1.f / fmaxf((float)n, 1.f);
    float m0 = a0 * inv_cnt, m1 = a1 * inv_cnt, m2 = a2 * inv_cnt;
    float tot = block_sum(m0 * m0 + m1 * m1 + m2 * m2, red);
    float sc2 = (n > 0) ? 1.f / fmaxf(sqrtf(tot), 1e-12f) : 0.f;
    size_t b = (size_t)cls * DIM;
    proto_bf[b + tid]       = f2bf(m0 * sc2);
    proto_bf[b + tid + 256] = f2bf(m1 * sc2);
    proto_bf[b + tid + 512] = f2bf(m2 * sc2);
}

// ---------- cos GEMM (bf16 x bf16, glds both) with fused exp -> logits ----------
// grid = (CPAD/128, B_ROWS/128); same 2-phase dbuf pipeline + XCD swizzle
__global__ __launch_bounds__(256)
void cos_gemm_kernel(const u16* __restrict__ Ab, const u16* __restrict__ Pb,
                     float* __restrict__ logits) {
    __shared__ u16 As[2][128 * 64];
    __shared__ u16 Bs[2][128 * 64];
    const int tid  = threadIdx.x;
    const int wave = tid >> 6, lane = tid & 63;
    const int fq = lane >> 4, fr = lane & 15;

    const int swz = xcd_swizzle();
    const int blk_m = (swz / gridDim.x) * 128;
    const int blk_n = (swz % gridDim.x) * 128;

    const int wm = (wave & 1) * 64, wn = (wave >> 1) * 64;

    v4f acc[4][4];
    #pragma unroll
    for (int i = 0; i < 4; i++)
        #pragma unroll
        for (int j = 0; j < 4; j++) acc[i][j] = (v4f){0.f, 0.f, 0.f, 0.f};

    const int rb = lane >> 3;
    const int cb = (lane & 7) * 8;
    const u16* gA = Ab + (size_t)(blk_m + wave * 8 + rb) * DIM + cb;
    const u16* gB = Pb + (size_t)(blk_n + wave * 8 + rb) * DIM + cb;

    auto STAGE = [&](int buf, int k0) {
        #pragma unroll
        for (int p = 0; p < 4; p++) {
            glds16(gA + (size_t)p * 32 * DIM + k0, &As[buf][p * 2048 + wave * 512]);
            glds16(gB + (size_t)p * 32 * DIM + k0, &Bs[buf][p * 2048 + wave * 512]);
        }
    };
    auto COMPUTE = [&](int buf) {
        #pragma unroll
        for (int ks = 0; ks < 2; ks++) {
            const int kk = ks * 32;
            v8bf af[4], bfr[4];
            #pragma unroll
            for (int i = 0; i < 4; i++) {
                af[i]  = *(const v8bf*)(&As[buf][(wm + i * 16 + fr) * 64 + kk + fq * 8]);
                bfr[i] = *(const v8bf*)(&Bs[buf][(wn + i * 16 + fr) * 64 + kk + fq * 8]);
            }
            #pragma unroll
            for (int i = 0; i < 4; i++)
                #pragma unroll
                for (int j = 0; j < 4; j++)
                    acc[i][j] = __builtin_amdgcn_mfma_f32_16x16x32_bf16(
                        af[i], bfr[j], acc[i][j], 0, 0, 0);
        }
    };

    STAGE(0, 0);
    __syncthreads();
    int cur = 0;
    for (int k0 = 64; k0 < DIM; k0 += 64) {
        STAGE(cur ^ 1, k0);
        COMPUTE(cur);
        __syncthreads();
        cur ^= 1;
    }
    COMPUTE(cur);

    #pragma unroll
    for (int i = 0; i < 4; i++) {
        int r0 = blk_m + wm + i * 16 + fq * 4;
        #pragma unroll
        for (int j = 0; j < 4; j++) {
            int col = blk_n + wn + j * 16 + fr;
            if (col < N_CLS) {
                #pragma unroll
                for (int r2 = 0; r2 < 4; r2++) {
                    float c = acc[i][j][r2];
                    logits[(size_t)(r0 + r2) * N_CLS + col] =
                        __expf(32.0f * (c - 1.0f)) * (1.0f / 0.11f);
                }
            }
        }
    }
}

// ---------- softmax over logits rows ----------
__global__ __launch_bounds__(256)
void softmax_kernel(const float* __restrict__ logits, float* __restrict__ predicts) {
    __shared__ float redm[4];
    __shared__ float reds[4];
    int row = blockIdx.x, tid = threadIdx.x;
    const float* lr = logits + (size_t)row * N_CLS;
    float4 lg = make_float4(-1.f, -1.f, -1.f, -1.f);
    bool act = tid < N_CLS / 4;   // 250
    if (act) lg = *(const float4*)(lr + tid * 4);
    float mx = fmaxf(fmaxf(lg.x, lg.y), fmaxf(lg.z, lg.w));  // logits >= 0
    float mxt = block_max(mx, redm);
    float4 e = make_float4(0.f, 0.f, 0.f, 0.f);
    float s = 0.f;
    if (act) {
        e.x = __expf(lg.x - mxt); e.y = __expf(lg.y - mxt);
        e.z = __expf(lg.z - mxt); e.w = __expf(lg.w - mxt);
        s = e.x + e.y + e.z + e.w;
    }
    float st = block_sum(s, reds);
    float inv = 1.f / st;
    if (act) {
        float4 o; o.x = e.x * inv; o.y = e.y * inv; o.z = e.z * inv; o.w = e.w * inv;
        *(float4*)(predicts + (size_t)row * N_CLS + tid * 4) = o;
    }
}

// ---------- launch ----------
extern "C" void kernel_launch(void* const* d_in, const int* in_sizes, int n_in,
                              void* d_out, int out_size, void* d_ws, size_t ws_size,
                              hipStream_t stream) {
    const float* x      = (const float*)d_in[0];
    const float* sup    = (const float*)d_in[1];
    const int*   labels = (const int*)d_in[2];
    const float* W      = (const float*)d_in[3];
    const float* bias   = (const float*)d_in[4];

    float* predicts = (float*)d_out;
    float* logits   = predicts + (size_t)B_ROWS * N_CLS;
    float* emb      = logits + (size_t)B_ROWS * N_CLS;   // 8192x768 fp32

    char* ws = (char*)d_ws;
    size_t off = 0;
    u16*   w_bf     = (u16*)(ws + off);   off += (size_t)DIM * DIM * 2;
    u16*   x_bf     = (u16*)(ws + off);   off += (size_t)B_ROWS * DIM * 2;
    u16*   sup_bf   = (u16*)(ws + off);   off += (size_t)MSUP_PAD * DIM * 2;
    u16*   val_x    = (u16*)(ws + off);   off += (size_t)B_ROWS * DIM * 2;
    u16*   val_sup  = (u16*)(ws + off);   off += (size_t)MSUP_PAD * DIM * 2;
    u16*   emb_bf   = (u16*)(ws + off);   off += (size_t)B_ROWS * DIM * 2;
    u16*   proto_bf = (u16*)(ws + off);   off += (size_t)CPAD * DIM * 2;
    float* ss_sup   = (float*)(ws + off); off += (size_t)MSUP_PAD * 4;
    float* ss_x     = (float*)(ws + off); off += (size_t)B_ROWS * 4;

    // zero row-sum-of-squares accumulators (contiguous)
    hipMemsetAsync(ss_sup, 0, ((size_t)MSUP_PAD + B_ROWS) * 4, stream);

    // bf16 conversions (4 rows per 256-thr block)
    conv_pad_kernel<<<DIM / 4,      256, 0, stream>>>(W,   w_bf,   DIM);
    conv_pad_kernel<<<B_ROWS / 4,   256, 0, stream>>>(x,   x_bf,   B_ROWS);
    conv_pad_kernel<<<MSUP_PAD / 4, 256, 0, stream>>>(sup, sup_bf, N_SUP);

    // adapter GEMMs (val = silu(A@W^T+b)+A, bf16; per-row ss)
    adapter_gemm_kernel<<<dim3(DIM / 128, B_ROWS / 128), 256, 0, stream>>>(
        x_bf, w_bf, bias, val_x, ss_x);
    adapter_gemm_kernel<<<dim3(DIM / 128, MSUP_PAD / 128), 256, 0, stream>>>(
        sup_bf, w_bf, bias, val_sup, ss_sup);

    // x normalize -> emb (fp32, d_out) + emb_bf
    norm_x_kernel<<<B_ROWS, 192, 0, stream>>>(val_x, ss_x, emb, emb_bf);

    // prototypes (rows >= N_CLS get zeros via n==0 path)
    proto_kernel<<<CPAD, 256, 0, stream>>>(val_sup, ss_sup, labels, proto_bf);

    // cos + exp -> logits (d_out), then softmax -> predicts (d_out)
    cos_gemm_kernel<<<dim3(CPAD / 128, B_ROWS / 128), 256, 0, stream>>>(
        emb_bf, proto_bf, logits);
    softmax_kernel<<<B_ROWS, 256, 0, stream>>>(logits, predicts);
}